// Round 1
// baseline (1154.325 us; speedup 1.0000x reference)
//
#include <hip/hip_runtime.h>

// MessagePassingNet on MI355X — Round 1: fp32 register-tiled baseline.
// Edge MLP (1M x [128->64->64->64]) + atomic scatter + atom readout + mol sum.
// fp32 VALU-bound by design this round (no fp32 MFMA on CDNA4).

constexpr int N_ATOMS = 131072;
constexpr int N_EDGES = 1048576;
constexpr int DD      = 64;     // atom state dim
constexpr int OUTD    = 16;
constexpr int N_MOLS  = 4096;
constexpr int PADE    = 68;     // padded LDS row (floats): mult of 4 (b128 align), breaks pow2 strides

#define DEV_INLINE __device__ __forceinline__

DEV_INLINE float relu(float x) { return x > 0.f ? x : 0.f; }

DEV_INLINE void fma16(float acc[4][4], float4 a, float4 b) {
  const float av[4] = {a.x, a.y, a.z, a.w};
  const float bv[4] = {b.x, b.y, b.z, b.w};
#pragma unroll
  for (int i = 0; i < 4; ++i)
#pragma unroll
    for (int j = 0; j < 4; ++j) acc[i][j] += av[i] * bv[j];
}

DEV_INLINE void zero_acc(float acc[4][4]) {
#pragma unroll
  for (int i = 0; i < 4; ++i)
#pragma unroll
    for (int j = 0; j < 4; ++j) acc[i][j] = 0.f;
}

// ---------------------------------------------------------------------------
// Edge kernel: one WG = 64 edges. featT[128][PADE] holds concat(dst,src) state
// transposed (k-major) so GEMM A-reads are float4-contiguous in the edge dim.
// Weights read from global (L1-hot: <=32KB per layer, shared per CU).
// ---------------------------------------------------------------------------
__global__ __launch_bounds__(256, 3)
void edge_kernel(const float* __restrict__ atom_states,
                 const int* __restrict__ edge_src,
                 const int* __restrict__ edge_dst,
                 const float* __restrict__ w0, const float* __restrict__ b0,
                 const float* __restrict__ w1, const float* __restrict__ b1,
                 const float* __restrict__ w2, const float* __restrict__ b2,
                 float* __restrict__ new_states)
{
  __shared__ float featT[128 * PADE];  // layer0 input; reused as h2T (rows 0..63)
  __shared__ float hT[64 * PADE];      // layer1 input
  __shared__ float bias[192];

  const int t  = threadIdx.x;
  const int e0 = blockIdx.x * 64;

  if (t < 64) { bias[t] = b0[t]; bias[64 + t] = b1[t]; bias[128 + t] = b2[t]; }

  // ---- gather stage: 2 threads per (edge, side); each copies 32 floats
  {
    const int job  = t >> 1;          // 0..127
    const int e    = job & 63;
    const int s    = job >> 6;        // 0 = dst side (cols 0..63), 1 = src side
    const int k0   = (t & 1) * 32;
    const int atom = (s ? edge_src : edge_dst)[e0 + e];
    const float4* src4 = (const float4*)(atom_states + (size_t)atom * DD + k0);
#pragma unroll
    for (int f = 0; f < 8; ++f) {
      float4 v = src4[f];
      const int kr = s * 64 + k0 + f * 4;
      featT[(kr + 0) * PADE + e] = v.x;
      featT[(kr + 1) * PADE + e] = v.y;
      featT[(kr + 2) * PADE + e] = v.z;
      featT[(kr + 3) * PADE + e] = v.w;
    }
  }
  __syncthreads();

  const int tx = t & 15;   // hidden-col group (4 cols)
  const int ty = t >> 4;   // edge-row group (4 rows)

  float acc[4][4];

  // ---- layer 0: [64 x 128] @ [128 x 64]
  zero_acc(acc);
#pragma unroll 8
  for (int k = 0; k < 128; ++k) {
    float4 a  = *(const float4*)&featT[k * PADE + ty * 4];
    float4 bw = *(const float4*)&w0[k * 64 + tx * 4];
    fma16(acc, a, bw);
  }
  // relu+bias, transpose into hT (different buffer than featT -> no barrier before writes)
#pragma unroll
  for (int j = 0; j < 4; ++j) {
    const float bb = bias[tx * 4 + j];
    float4 v = make_float4(relu(acc[0][j] + bb), relu(acc[1][j] + bb),
                           relu(acc[2][j] + bb), relu(acc[3][j] + bb));
    *(float4*)&hT[(tx * 4 + j) * PADE + ty * 4] = v;
  }
  __syncthreads();

  // ---- layer 1: [64 x 64] @ [64 x 64], output (h2T) into featT rows 0..63
  zero_acc(acc);
#pragma unroll 8
  for (int k = 0; k < 64; ++k) {
    float4 a  = *(const float4*)&hT[k * PADE + ty * 4];
    float4 bw = *(const float4*)&w1[k * 64 + tx * 4];
    fma16(acc, a, bw);
  }
#pragma unroll
  for (int j = 0; j < 4; ++j) {
    const float bb = bias[64 + tx * 4 + j];
    float4 v = make_float4(relu(acc[0][j] + bb), relu(acc[1][j] + bb),
                           relu(acc[2][j] + bb), relu(acc[3][j] + bb));
    *(float4*)&featT[(tx * 4 + j) * PADE + ty * 4] = v;
  }
  __syncthreads();

  // ---- layer 2: [64 x 64] @ [64 x 64] -> messages, atomic scatter by dst
  zero_acc(acc);
#pragma unroll 8
  for (int k = 0; k < 64; ++k) {
    float4 a  = *(const float4*)&featT[k * PADE + ty * 4];
    float4 bw = *(const float4*)&w2[k * 64 + tx * 4];
    fma16(acc, a, bw);
  }
#pragma unroll
  for (int i = 0; i < 4; ++i) {
    const int dst = edge_dst[e0 + ty * 4 + i];
    float* outp = new_states + (size_t)dst * DD + tx * 4;
#pragma unroll
    for (int j = 0; j < 4; ++j) {
      atomicAdd(outp + j, relu(acc[i][j] + bias[128 + tx * 4 + j]));
    }
  }
}

// ---------------------------------------------------------------------------
// Atom kernel: one WG = 64 atoms = exactly 2 molecules (atom_seg = arange/32).
// fc1 -> fc2 -> out(16) -> in-LDS per-molecule sum -> direct store (no atomics).
// ---------------------------------------------------------------------------
__global__ __launch_bounds__(256, 3)
void atom_kernel(const float* __restrict__ x,
                 const float* __restrict__ w1, const float* __restrict__ b1,
                 const float* __restrict__ w2, const float* __restrict__ b2,
                 const float* __restrict__ wo, const float* __restrict__ bo,
                 float* __restrict__ out)
{
  __shared__ float xT[64 * PADE];   // input transposed; reused for h2
  __shared__ float hT[64 * PADE];
  __shared__ float oS[64 * 17];
  __shared__ float bias[144];

  const int t  = threadIdx.x;
  const int a0 = blockIdx.x * 64;

  if (t < 64) { bias[t] = b1[t]; bias[64 + t] = b2[t]; }
  if (t < 16) { bias[128 + t] = bo[t]; }

  // ---- stage: 4 threads per atom row, 16 floats each
  {
    const int r  = t & 63;
    const int k0 = (t >> 6) * 16;
    const float4* src4 = (const float4*)(x + (size_t)(a0 + r) * DD + k0);
#pragma unroll
    for (int f = 0; f < 4; ++f) {
      float4 v = src4[f];
      const int kr = k0 + f * 4;
      xT[(kr + 0) * PADE + r] = v.x;
      xT[(kr + 1) * PADE + r] = v.y;
      xT[(kr + 2) * PADE + r] = v.z;
      xT[(kr + 3) * PADE + r] = v.w;
    }
  }
  __syncthreads();

  const int tx = t & 15;
  const int ty = t >> 4;
  float acc[4][4];

  // ---- fc1
  zero_acc(acc);
#pragma unroll 8
  for (int k = 0; k < 64; ++k) {
    float4 a  = *(const float4*)&xT[k * PADE + ty * 4];
    float4 bw = *(const float4*)&w1[k * 64 + tx * 4];
    fma16(acc, a, bw);
  }
#pragma unroll
  for (int j = 0; j < 4; ++j) {
    const float bb = bias[tx * 4 + j];
    float4 v = make_float4(relu(acc[0][j] + bb), relu(acc[1][j] + bb),
                           relu(acc[2][j] + bb), relu(acc[3][j] + bb));
    *(float4*)&hT[(tx * 4 + j) * PADE + ty * 4] = v;
  }
  __syncthreads();

  // ---- fc2 (back into xT)
  zero_acc(acc);
#pragma unroll 8
  for (int k = 0; k < 64; ++k) {
    float4 a  = *(const float4*)&hT[k * PADE + ty * 4];
    float4 bw = *(const float4*)&w2[k * 64 + tx * 4];
    fma16(acc, a, bw);
  }
#pragma unroll
  for (int j = 0; j < 4; ++j) {
    const float bb = bias[64 + tx * 4 + j];
    float4 v = make_float4(relu(acc[0][j] + bb), relu(acc[1][j] + bb),
                           relu(acc[2][j] + bb), relu(acc[3][j] + bb));
    *(float4*)&xT[(tx * 4 + j) * PADE + ty * 4] = v;
  }
  __syncthreads();

  // ---- out layer: [64 x 64] @ [64 x 16]; thread -> (row = t>>2, 4 cols)
  {
    const int r  = t >> 2;
    const int c4 = (t & 3) * 4;
    float o4[4] = {0.f, 0.f, 0.f, 0.f};
#pragma unroll 8
    for (int k = 0; k < 64; ++k) {
      const float a = xT[k * PADE + r];
      float4 bw = *(const float4*)&wo[k * OUTD + c4];
      o4[0] += a * bw.x; o4[1] += a * bw.y; o4[2] += a * bw.z; o4[3] += a * bw.w;
    }
#pragma unroll
    for (int j = 0; j < 4; ++j) {
      oS[r * 17 + c4 + j] = relu(o4[j] + bias[128 + c4 + j]);
    }
  }
  __syncthreads();

  // ---- molecule reduction: 2 molecules x 16 cols
  if (t < 32) {
    const int m = t >> 4;
    const int c = t & 15;
    float s = 0.f;
#pragma unroll
    for (int a = 0; a < 32; ++a) s += oS[(m * 32 + a) * 17 + c];
    out[(blockIdx.x * 2 + m) * OUTD + c] = s;
  }
}

// ---------------------------------------------------------------------------
extern "C" void kernel_launch(void* const* d_in, const int* in_sizes, int n_in,
                              void* d_out, int out_size, void* d_ws, size_t ws_size,
                              hipStream_t stream) {
  const float* atom_states = (const float*)d_in[0];
  const int*   edge_src    = (const int*)d_in[1];
  const int*   edge_dst    = (const int*)d_in[2];
  // d_in[3] = atom_seg (arange/32, structure relied upon: 32 contiguous atoms/mol)
  const float* ms0_w = (const float*)d_in[4];
  const float* ms0_b = (const float*)d_in[5];
  const float* ms1_w = (const float*)d_in[6];
  const float* ms1_b = (const float*)d_in[7];
  const float* ms2_w = (const float*)d_in[8];
  const float* ms2_b = (const float*)d_in[9];
  const float* fc1_w = (const float*)d_in[10];
  const float* fc1_b = (const float*)d_in[11];
  const float* fc2_w = (const float*)d_in[12];
  const float* fc2_b = (const float*)d_in[13];
  const float* out_w = (const float*)d_in[14];
  const float* out_b = (const float*)d_in[15];

  float* new_states = (float*)d_ws;  // [N_ATOMS][64] fp32 = 32 MB

  hipMemsetAsync(new_states, 0, (size_t)N_ATOMS * DD * sizeof(float), stream);

  edge_kernel<<<N_EDGES / 64, 256, 0, stream>>>(
      atom_states, edge_src, edge_dst,
      ms0_w, ms0_b, ms1_w, ms1_b, ms2_w, ms2_b, new_states);

  atom_kernel<<<N_ATOMS / 64, 256, 0, stream>>>(
      new_states, fc1_w, fc1_b, fc2_w, fc2_b, out_w, out_b, (float*)d_out);
}

// Round 2
// 795.070 us; speedup vs baseline: 1.4519x; 1.4519x over previous
//
#include <hip/hip_runtime.h>

// MessagePassingNet on MI355X — Round 2: dst-sorted edges (counting sort) +
// LDS segmented reduction -> ~2M atomics instead of 67M. fp32 VALU GEMMs.

constexpr int N_ATOMS = 131072;
constexpr int N_EDGES = 1048576;
constexpr int DD      = 64;
constexpr int OUTD    = 16;
constexpr int PADE    = 68;   // padded LDS row (floats)

#define DEV_INLINE __device__ __forceinline__

DEV_INLINE float relu(float x) { return x > 0.f ? x : 0.f; }

DEV_INLINE void fma16(float acc[4][4], float4 a, float4 b) {
  const float av[4] = {a.x, a.y, a.z, a.w};
  const float bv[4] = {b.x, b.y, b.z, b.w};
#pragma unroll
  for (int i = 0; i < 4; ++i)
#pragma unroll
    for (int j = 0; j < 4; ++j) acc[i][j] += av[i] * bv[j];
}

DEV_INLINE void zero_acc(float acc[4][4]) {
#pragma unroll
  for (int i = 0; i < 4; ++i)
#pragma unroll
    for (int j = 0; j < 4; ++j) acc[i][j] = 0.f;
}

// ===========================================================================
// Counting-sort build: histogram -> block sums -> scan -> per-elem scan ->
// scatter edge ids grouped by dst.
// ===========================================================================
__global__ void hist_kernel(const int* __restrict__ edge_dst,
                            int* __restrict__ counters) {
  int i = blockIdx.x * blockDim.x + threadIdx.x;
  if (i < N_EDGES) atomicAdd(&counters[edge_dst[i]], 1);
}

__global__ void blocksum_kernel(const int* __restrict__ counters,
                                int* __restrict__ partial) {
  __shared__ int s[256];
  int t = threadIdx.x;
  s[t] = counters[blockIdx.x * 256 + t];
  __syncthreads();
  for (int off = 128; off > 0; off >>= 1) {
    if (t < off) s[t] += s[t + off];
    __syncthreads();
  }
  if (t == 0) partial[blockIdx.x] = s[0];
}

__global__ void scanpartial_kernel(int* __restrict__ partial) {
  __shared__ int s[512];
  int t = threadIdx.x;
  s[t] = partial[t];
  __syncthreads();
  for (int off = 1; off < 512; off <<= 1) {
    int x = (t >= off) ? s[t - off] : 0;
    __syncthreads();
    s[t] += x;
    __syncthreads();
  }
  partial[t] = (t == 0) ? 0 : s[t - 1];   // exclusive scan in place
}

__global__ void scanwrite_kernel(const int* __restrict__ counters,
                                 const int* __restrict__ partial,
                                 int* __restrict__ cursor) {
  __shared__ int s[256];
  int t = threadIdx.x, b = blockIdx.x;
  int v = counters[b * 256 + t];
  s[t] = v;
  __syncthreads();
  for (int off = 1; off < 256; off <<= 1) {
    int x = (t >= off) ? s[t - off] : 0;
    __syncthreads();
    s[t] += x;
    __syncthreads();
  }
  cursor[b * 256 + t] = partial[b] + s[t] - v;  // exclusive
}

__global__ void scatter_kernel(const int* __restrict__ edge_dst,
                               int* __restrict__ cursor,
                               int* __restrict__ eids) {
  int i = blockIdx.x * blockDim.x + threadIdx.x;
  if (i < N_EDGES) {
    int pos = atomicAdd(&cursor[edge_dst[i]], 1);
    eids[pos] = i;
  }
}

// ===========================================================================
// Edge kernel (CSR order): one WG = 64 dst-sorted edges. Single 128x68 LDS
// buffer, ping-pong halves. Segmented reduce in LDS; interior runs -> plain
// store (exclusive owner), boundary runs -> atomicAdd.
// ===========================================================================
__global__ __launch_bounds__(256, 4)
void edge_kernel_csr(const float* __restrict__ atom_states,
                     const int* __restrict__ edge_src,
                     const int* __restrict__ edge_dst,
                     const int* __restrict__ eids,
                     const float* __restrict__ w0, const float* __restrict__ b0,
                     const float* __restrict__ w1, const float* __restrict__ b1,
                     const float* __restrict__ w2, const float* __restrict__ b2,
                     float* __restrict__ new_states)
{
  __shared__ float featT[128 * PADE];
  __shared__ float bias[192];
  __shared__ int   eidS[64];
  __shared__ int   dstS[64];
  __shared__ int   segStart[65];
  __shared__ int   segCount;

  const int t  = threadIdx.x;
  const int e0 = blockIdx.x * 64;

  if (t < 64) {
    bias[t] = b0[t]; bias[64 + t] = b1[t]; bias[128 + t] = b2[t];
    int e = eids[e0 + t];
    eidS[t] = e;
    dstS[t] = edge_dst[e];
  }
  __syncthreads();

  // segment detection (wave 0 only); consumed after later barriers
  if (t < 64) {
    bool isStart = (t == 0) || (dstS[t] != dstS[t - 1]);
    unsigned long long m = __ballot(isStart);
    if (isStart) {
      unsigned long long below = (t == 0) ? 0ull : (m & ((1ull << t) - 1ull));
      segStart[__popcll(below)] = t;
    }
    if (t == 0) {
      int ns = __popcll(m);
      segCount = ns;
      segStart[ns] = 64;
    }
  }

  // ---- gather: 2 threads per (edge, side), 32 floats each -> featT k-major
  {
    const int job  = t >> 1;
    const int e    = job & 63;
    const int s    = job >> 6;          // 0=dst side (k 0..63), 1=src side
    const int k0   = (t & 1) * 32;
    const int atom = s ? edge_src[eidS[e]] : dstS[e];
    const float4* src4 = (const float4*)(atom_states + (size_t)atom * DD + k0);
#pragma unroll
    for (int f = 0; f < 8; ++f) {
      float4 v = src4[f];
      const int kr = s * 64 + k0 + f * 4;
      featT[(kr + 0) * PADE + e] = v.x;
      featT[(kr + 1) * PADE + e] = v.y;
      featT[(kr + 2) * PADE + e] = v.z;
      featT[(kr + 3) * PADE + e] = v.w;
    }
  }
  __syncthreads();

  const int tx = t & 15;
  const int ty = t >> 4;
  float acc[4][4];

  // ---- layer 0: reads rows 0..127
  zero_acc(acc);
#pragma unroll 8
  for (int k = 0; k < 128; ++k) {
    float4 a  = *(const float4*)&featT[k * PADE + ty * 4];
    float4 bw = *(const float4*)&w0[k * 64 + tx * 4];
    fma16(acc, a, bw);
  }
  __syncthreads();   // all rows dead
  // h -> rows 64..127
#pragma unroll
  for (int j = 0; j < 4; ++j) {
    const float bb = bias[tx * 4 + j];
    float4 v = make_float4(relu(acc[0][j] + bb), relu(acc[1][j] + bb),
                           relu(acc[2][j] + bb), relu(acc[3][j] + bb));
    *(float4*)&featT[(64 + tx * 4 + j) * PADE + ty * 4] = v;
  }
  __syncthreads();

  // ---- layer 1: reads rows 64..127; h2 -> rows 0..63 (disjoint, no barrier)
  zero_acc(acc);
#pragma unroll 8
  for (int k = 0; k < 64; ++k) {
    float4 a  = *(const float4*)&featT[(64 + k) * PADE + ty * 4];
    float4 bw = *(const float4*)&w1[k * 64 + tx * 4];
    fma16(acc, a, bw);
  }
#pragma unroll
  for (int j = 0; j < 4; ++j) {
    const float bb = bias[64 + tx * 4 + j];
    float4 v = make_float4(relu(acc[0][j] + bb), relu(acc[1][j] + bb),
                           relu(acc[2][j] + bb), relu(acc[3][j] + bb));
    *(float4*)&featT[(tx * 4 + j) * PADE + ty * 4] = v;
  }
  __syncthreads();   // h2 complete, L1 reads of rows 64..127 done

  // ---- layer 2: reads rows 0..63; messages -> rows 64..127 (row-major)
  zero_acc(acc);
#pragma unroll 8
  for (int k = 0; k < 64; ++k) {
    float4 a  = *(const float4*)&featT[k * PADE + ty * 4];
    float4 bw = *(const float4*)&w2[k * 64 + tx * 4];
    fma16(acc, a, bw);
  }
#pragma unroll
  for (int i = 0; i < 4; ++i) {
    float4 v = make_float4(relu(acc[i][0] + bias[128 + tx * 4 + 0]),
                           relu(acc[i][1] + bias[128 + tx * 4 + 1]),
                           relu(acc[i][2] + bias[128 + tx * 4 + 2]),
                           relu(acc[i][3] + bias[128 + tx * 4 + 3]));
    *(float4*)&featT[(64 + ty * 4 + i) * PADE + tx * 4] = v;
  }
  __syncthreads();

  // ---- segmented reduction over dst runs; store interior, atomic boundary
  {
    const int c = t & 63;
    const int g = t >> 6;
    const int ns = segCount;
    for (int s = g; s < ns; s += 4) {
      const int r0 = segStart[s], r1 = segStart[s + 1];
      float sum = 0.f;
      for (int r = r0; r < r1; ++r) sum += featT[(64 + r) * PADE + c];
      float* p = new_states + (size_t)dstS[r0] * DD + c;
      if (s == 0 || s == ns - 1) atomicAdd(p, sum);
      else *p = sum;   // run fully inside this tile -> exclusive owner
    }
  }
}

// ===========================================================================
// Fallback edge kernel (Round-1 atomic scatter) if ws too small for the sort.
// ===========================================================================
__global__ __launch_bounds__(256, 3)
void edge_kernel_atomic(const float* __restrict__ atom_states,
                        const int* __restrict__ edge_src,
                        const int* __restrict__ edge_dst,
                        const float* __restrict__ w0, const float* __restrict__ b0,
                        const float* __restrict__ w1, const float* __restrict__ b1,
                        const float* __restrict__ w2, const float* __restrict__ b2,
                        float* __restrict__ new_states)
{
  __shared__ float featT[128 * PADE];
  __shared__ float hT[64 * PADE];
  __shared__ float bias[192];

  const int t  = threadIdx.x;
  const int e0 = blockIdx.x * 64;

  if (t < 64) { bias[t] = b0[t]; bias[64 + t] = b1[t]; bias[128 + t] = b2[t]; }
  {
    const int job  = t >> 1;
    const int e    = job & 63;
    const int s    = job >> 6;
    const int k0   = (t & 1) * 32;
    const int atom = (s ? edge_src : edge_dst)[e0 + e];
    const float4* src4 = (const float4*)(atom_states + (size_t)atom * DD + k0);
#pragma unroll
    for (int f = 0; f < 8; ++f) {
      float4 v = src4[f];
      const int kr = s * 64 + k0 + f * 4;
      featT[(kr + 0) * PADE + e] = v.x;
      featT[(kr + 1) * PADE + e] = v.y;
      featT[(kr + 2) * PADE + e] = v.z;
      featT[(kr + 3) * PADE + e] = v.w;
    }
  }
  __syncthreads();

  const int tx = t & 15;
  const int ty = t >> 4;
  float acc[4][4];

  zero_acc(acc);
#pragma unroll 8
  for (int k = 0; k < 128; ++k) {
    float4 a  = *(const float4*)&featT[k * PADE + ty * 4];
    float4 bw = *(const float4*)&w0[k * 64 + tx * 4];
    fma16(acc, a, bw);
  }
#pragma unroll
  for (int j = 0; j < 4; ++j) {
    const float bb = bias[tx * 4 + j];
    float4 v = make_float4(relu(acc[0][j] + bb), relu(acc[1][j] + bb),
                           relu(acc[2][j] + bb), relu(acc[3][j] + bb));
    *(float4*)&hT[(tx * 4 + j) * PADE + ty * 4] = v;
  }
  __syncthreads();

  zero_acc(acc);
#pragma unroll 8
  for (int k = 0; k < 64; ++k) {
    float4 a  = *(const float4*)&hT[k * PADE + ty * 4];
    float4 bw = *(const float4*)&w1[k * 64 + tx * 4];
    fma16(acc, a, bw);
  }
#pragma unroll
  for (int j = 0; j < 4; ++j) {
    const float bb = bias[64 + tx * 4 + j];
    float4 v = make_float4(relu(acc[0][j] + bb), relu(acc[1][j] + bb),
                           relu(acc[2][j] + bb), relu(acc[3][j] + bb));
    *(float4*)&featT[(tx * 4 + j) * PADE + ty * 4] = v;
  }
  __syncthreads();

  zero_acc(acc);
#pragma unroll 8
  for (int k = 0; k < 64; ++k) {
    float4 a  = *(const float4*)&featT[k * PADE + ty * 4];
    float4 bw = *(const float4*)&w2[k * 64 + tx * 4];
    fma16(acc, a, bw);
  }
#pragma unroll
  for (int i = 0; i < 4; ++i) {
    const int dst = edge_dst[e0 + ty * 4 + i];
    float* outp = new_states + (size_t)dst * DD + tx * 4;
#pragma unroll
    for (int j = 0; j < 4; ++j)
      atomicAdd(outp + j, relu(acc[i][j] + bias[128 + tx * 4 + j]));
  }
}

// ===========================================================================
// Atom readout: one WG = 64 atoms = 2 molecules. No atomics.
// ===========================================================================
__global__ __launch_bounds__(256, 4)
void atom_kernel(const float* __restrict__ x,
                 const float* __restrict__ w1, const float* __restrict__ b1,
                 const float* __restrict__ w2, const float* __restrict__ b2,
                 const float* __restrict__ wo, const float* __restrict__ bo,
                 float* __restrict__ out)
{
  __shared__ float xT[64 * PADE];
  __shared__ float hT[64 * PADE];
  __shared__ float oS[64 * 17];
  __shared__ float bias[144];

  const int t  = threadIdx.x;
  const int a0 = blockIdx.x * 64;

  if (t < 64) { bias[t] = b1[t]; bias[64 + t] = b2[t]; }
  if (t < 16) { bias[128 + t] = bo[t]; }

  {
    const int r  = t & 63;
    const int k0 = (t >> 6) * 16;
    const float4* src4 = (const float4*)(x + (size_t)(a0 + r) * DD + k0);
#pragma unroll
    for (int f = 0; f < 4; ++f) {
      float4 v = src4[f];
      const int kr = k0 + f * 4;
      xT[(kr + 0) * PADE + r] = v.x;
      xT[(kr + 1) * PADE + r] = v.y;
      xT[(kr + 2) * PADE + r] = v.z;
      xT[(kr + 3) * PADE + r] = v.w;
    }
  }
  __syncthreads();

  const int tx = t & 15;
  const int ty = t >> 4;
  float acc[4][4];

  zero_acc(acc);
#pragma unroll 8
  for (int k = 0; k < 64; ++k) {
    float4 a  = *(const float4*)&xT[k * PADE + ty * 4];
    float4 bw = *(const float4*)&w1[k * 64 + tx * 4];
    fma16(acc, a, bw);
  }
#pragma unroll
  for (int j = 0; j < 4; ++j) {
    const float bb = bias[tx * 4 + j];
    float4 v = make_float4(relu(acc[0][j] + bb), relu(acc[1][j] + bb),
                           relu(acc[2][j] + bb), relu(acc[3][j] + bb));
    *(float4*)&hT[(tx * 4 + j) * PADE + ty * 4] = v;
  }
  __syncthreads();

  zero_acc(acc);
#pragma unroll 8
  for (int k = 0; k < 64; ++k) {
    float4 a  = *(const float4*)&hT[k * PADE + ty * 4];
    float4 bw = *(const float4*)&w2[k * 64 + tx * 4];
    fma16(acc, a, bw);
  }
#pragma unroll
  for (int j = 0; j < 4; ++j) {
    const float bb = bias[64 + tx * 4 + j];
    float4 v = make_float4(relu(acc[0][j] + bb), relu(acc[1][j] + bb),
                           relu(acc[2][j] + bb), relu(acc[3][j] + bb));
    *(float4*)&xT[(tx * 4 + j) * PADE + ty * 4] = v;
  }
  __syncthreads();

  {
    const int r  = t >> 2;
    const int c4 = (t & 3) * 4;
    float o4[4] = {0.f, 0.f, 0.f, 0.f};
#pragma unroll 8
    for (int k = 0; k < 64; ++k) {
      const float a = xT[k * PADE + r];
      float4 bw = *(const float4*)&wo[k * OUTD + c4];
      o4[0] += a * bw.x; o4[1] += a * bw.y; o4[2] += a * bw.z; o4[3] += a * bw.w;
    }
#pragma unroll
    for (int j = 0; j < 4; ++j)
      oS[r * 17 + c4 + j] = relu(o4[j] + bias[128 + c4 + j]);
  }
  __syncthreads();

  if (t < 32) {
    const int m = t >> 4;
    const int c = t & 15;
    float s = 0.f;
#pragma unroll
    for (int a = 0; a < 32; ++a) s += oS[(m * 32 + a) * 17 + c];
    out[(blockIdx.x * 2 + m) * OUTD + c] = s;
  }
}

// ===========================================================================
extern "C" void kernel_launch(void* const* d_in, const int* in_sizes, int n_in,
                              void* d_out, int out_size, void* d_ws, size_t ws_size,
                              hipStream_t stream) {
  const float* atom_states = (const float*)d_in[0];
  const int*   edge_src    = (const int*)d_in[1];
  const int*   edge_dst    = (const int*)d_in[2];
  const float* ms0_w = (const float*)d_in[4];
  const float* ms0_b = (const float*)d_in[5];
  const float* ms1_w = (const float*)d_in[6];
  const float* ms1_b = (const float*)d_in[7];
  const float* ms2_w = (const float*)d_in[8];
  const float* ms2_b = (const float*)d_in[9];
  const float* fc1_w = (const float*)d_in[10];
  const float* fc1_b = (const float*)d_in[11];
  const float* fc2_w = (const float*)d_in[12];
  const float* fc2_b = (const float*)d_in[13];
  const float* out_w = (const float*)d_in[14];
  const float* out_b = (const float*)d_in[15];

  char* ws = (char*)d_ws;
  float* new_states = (float*)ws;
  size_t off = (size_t)N_ATOMS * DD * sizeof(float);          // 32 MiB
  int* eids     = (int*)(ws + off); off += (size_t)N_EDGES * 4;   // +4 MiB
  int* counters = (int*)(ws + off); off += (size_t)N_ATOMS * 4;   // +512 KiB
  int* cursor   = (int*)(ws + off); off += (size_t)N_ATOMS * 4;   // +512 KiB
  int* partial  = (int*)(ws + off); off += 512 * 4;               // +2 KiB
  const size_t need = off;

  hipMemsetAsync(new_states, 0, (size_t)N_ATOMS * DD * sizeof(float), stream);

  if (ws_size >= need) {
    hipMemsetAsync(counters, 0, (size_t)N_ATOMS * 4, stream);
    hist_kernel<<<N_EDGES / 256, 256, 0, stream>>>(edge_dst, counters);
    blocksum_kernel<<<512, 256, 0, stream>>>(counters, partial);
    scanpartial_kernel<<<1, 512, 0, stream>>>(partial);
    scanwrite_kernel<<<512, 256, 0, stream>>>(counters, partial, cursor);
    scatter_kernel<<<N_EDGES / 256, 256, 0, stream>>>(edge_dst, cursor, eids);
    edge_kernel_csr<<<N_EDGES / 64, 256, 0, stream>>>(
        atom_states, edge_src, edge_dst, eids,
        ms0_w, ms0_b, ms1_w, ms1_b, ms2_w, ms2_b, new_states);
  } else {
    edge_kernel_atomic<<<N_EDGES / 64, 256, 0, stream>>>(
        atom_states, edge_src, edge_dst,
        ms0_w, ms0_b, ms1_w, ms1_b, ms2_w, ms2_b, new_states);
  }

  atom_kernel<<<N_ATOMS / 64, 256, 0, stream>>>(
      new_states, fc1_w, fc1_b, fc2_w, fc2_b, out_w, out_b, (float*)d_out);
}

// Round 3
// 562.655 us; speedup vs baseline: 2.0516x; 1.4131x over previous
//
#include <hip/hip_runtime.h>

// MessagePassingNet on MI355X — Round 3: edge MLP on matrix cores via
// split-bf16 (hi/lo, 3-MFMA) + dst-sorted segmented reduction.

constexpr int N_ATOMS = 131072;
constexpr int N_EDGES = 1048576;
constexpr int DD      = 64;
constexpr int OUTD    = 16;
constexpr int SA      = 136;  // LDS row stride (halfwords) for 128-wide A / reuse as h2
constexpr int SH      = 72;   // LDS row stride (halfwords) for 64-wide h1
constexpr int PADE    = 68;   // fp32 LDS row stride (msg buf, atom kernel)

typedef __bf16 bf16x8 __attribute__((ext_vector_type(8)));
typedef float  f32x4  __attribute__((ext_vector_type(4)));

#define DEV_INLINE __device__ __forceinline__

DEV_INLINE float relu(float x) { return x > 0.f ? x : 0.f; }

DEV_INLINE unsigned short bfbits(float x) {
  __bf16 h = (__bf16)x;                       // RN convert
  return __builtin_bit_cast(unsigned short, h);
}
DEV_INLINE float bfval(unsigned short u) {
  unsigned int v = ((unsigned int)u) << 16;
  return __builtin_bit_cast(float, v);
}
DEV_INLINE f32x4 mfma16(bf16x8 a, bf16x8 b, f32x4 c) {
  return __builtin_amdgcn_mfma_f32_16x16x32_bf16(a, b, c, 0, 0, 0);
}
DEV_INLINE bf16x8 ldfrag(const unsigned short* p) {
  return *(const bf16x8*)p;
}

DEV_INLINE void fma16v(float acc[4][4], float4 a, float4 b) {
  const float av[4] = {a.x, a.y, a.z, a.w};
  const float bv[4] = {b.x, b.y, b.z, b.w};
#pragma unroll
  for (int i = 0; i < 4; ++i)
#pragma unroll
    for (int j = 0; j < 4; ++j) acc[i][j] += av[i] * bv[j];
}
DEV_INLINE void zero4x4(float acc[4][4]) {
#pragma unroll
  for (int i = 0; i < 4; ++i)
#pragma unroll
    for (int j = 0; j < 4; ++j) acc[i][j] = 0.f;
}

// ===========================================================================
// Counting sort (unchanged from Round 2)
// ===========================================================================
__global__ void hist_kernel(const int* __restrict__ edge_dst,
                            int* __restrict__ counters) {
  int i = blockIdx.x * blockDim.x + threadIdx.x;
  if (i < N_EDGES) atomicAdd(&counters[edge_dst[i]], 1);
}

__global__ void blocksum_kernel(const int* __restrict__ counters,
                                int* __restrict__ partial) {
  __shared__ int s[256];
  int t = threadIdx.x;
  s[t] = counters[blockIdx.x * 256 + t];
  __syncthreads();
  for (int off = 128; off > 0; off >>= 1) {
    if (t < off) s[t] += s[t + off];
    __syncthreads();
  }
  if (t == 0) partial[blockIdx.x] = s[0];
}

__global__ void scanpartial_kernel(int* __restrict__ partial) {
  __shared__ int s[512];
  int t = threadIdx.x;
  s[t] = partial[t];
  __syncthreads();
  for (int off = 1; off < 512; off <<= 1) {
    int x = (t >= off) ? s[t - off] : 0;
    __syncthreads();
    s[t] += x;
    __syncthreads();
  }
  partial[t] = (t == 0) ? 0 : s[t - 1];
}

__global__ void scanwrite_kernel(const int* __restrict__ counters,
                                 const int* __restrict__ partial,
                                 int* __restrict__ cursor) {
  __shared__ int s[256];
  int t = threadIdx.x, b = blockIdx.x;
  int v = counters[b * 256 + t];
  s[t] = v;
  __syncthreads();
  for (int off = 1; off < 256; off <<= 1) {
    int x = (t >= off) ? s[t - off] : 0;
    __syncthreads();
    s[t] += x;
    __syncthreads();
  }
  cursor[b * 256 + t] = partial[b] + s[t] - v;
}

__global__ void scatter_kernel(const int* __restrict__ edge_dst,
                               int* __restrict__ cursor,
                               int* __restrict__ eids) {
  int i = blockIdx.x * blockDim.x + threadIdx.x;
  if (i < N_EDGES) {
    int pos = atomicAdd(&cursor[edge_dst[i]], 1);
    eids[pos] = i;
  }
}

// ===========================================================================
// Weight prep: split fp32 weights to bf16 hi/lo, packed in MFMA B-fragment
// order. Fragment (layer, ntile j, kstep s): 64 lanes x 8 bf16 (consecutive k).
// Element: lane l -> B[k = s*32 + (l>>4)*8 + i][n = j*16 + (l&15)].
// Bases (elems): L0 = 0 (4x4 tiles), L1 = 8192 (4x2), L2 = 12288 (4x2).
// ===========================================================================
__global__ void weight_prep(const float* __restrict__ w0,
                            const float* __restrict__ w1,
                            const float* __restrict__ w2,
                            unsigned short* __restrict__ whi,
                            unsigned short* __restrict__ wlo) {
  int tid = blockIdx.x * blockDim.x + threadIdx.x;   // 0..2047
  const float* w; int base, K, rel;
  if (tid < 1024)      { w = w0; base = 0;     K = 128; rel = tid; }
  else if (tid < 1536) { w = w1; base = 8192;  K = 64;  rel = tid - 1024; }
  else                 { w = w2; base = 12288; K = 64;  rel = tid - 1536; }
  const int tile = rel >> 6, lane = rel & 63;
  const int ksteps = K / 32;
  const int j = tile / ksteps, s = tile % ksteps;
  const int n  = j * 16 + (lane & 15);
  const int kb = s * 32 + (lane >> 4) * 8;
  const int out = base + (tile * 64 + lane) * 8;
#pragma unroll
  for (int i = 0; i < 8; ++i) {
    float v = w[(kb + i) * 64 + n];
    unsigned short h = bfbits(v);
    whi[out + i] = h;
    wlo[out + i] = bfbits(v - bfval(h));
  }
}

// ===========================================================================
// Edge kernel (MFMA): WG = 64 dst-sorted edges, 4 waves x (16 rows, 64 cols).
// Split-bf16: acc += Alo*Bhi + Ahi*Blo + Ahi*Bhi per K-step.
// ===========================================================================
__global__ __launch_bounds__(256, 3)
void edge_kernel_mfma(const float* __restrict__ atom_states,
                      const int* __restrict__ edge_src,
                      const int* __restrict__ edge_dst,
                      const int* __restrict__ eids,
                      const unsigned short* __restrict__ whi,
                      const unsigned short* __restrict__ wlo,
                      const float* __restrict__ b0,
                      const float* __restrict__ b1,
                      const float* __restrict__ b2,
                      float* __restrict__ new_states)
{
  __shared__ __align__(16) unsigned short Ahi[64 * SA];   // features / h2 (hi)
  __shared__ __align__(16) unsigned short Alo[64 * SA];   // features / h2 (lo)
  __shared__ __align__(16) unsigned short Hbuf[2 * 64 * SH];  // h1 hi|lo; later msg fp32
  __shared__ int eidS[64], dstS[64], segStart[65], segCount;

  unsigned short* Hhi = Hbuf;
  unsigned short* Hlo = Hbuf + 64 * SH;
  float* msg = (float*)Hbuf;    // 64*PADE*4 = 17408 B <= 18432 B

  const int t  = threadIdx.x;
  const int e0 = blockIdx.x * 64;

  if (t < 64) { int e = eids[e0 + t]; eidS[t] = e; dstS[t] = edge_dst[e]; }
  __syncthreads();

  if (t < 64) {   // wave 0: segment detection
    bool isStart = (t == 0) || (dstS[t] != dstS[t - 1]);
    unsigned long long m = __ballot(isStart);
    if (isStart) {
      unsigned long long below = (t == 0) ? 0ull : (m & ((1ull << t) - 1ull));
      segStart[__popcll(below)] = t;
    }
    if (t == 0) { int ns = __popcll(m); segCount = ns; segStart[ns] = 64; }
  }

  // ---- gather + hi/lo split: 2 threads per (edge, side), 32 floats each
  {
    const int job  = t >> 1;
    const int e    = job & 63;
    const int side = job >> 6;          // 0 = dst (k 0..63), 1 = src (k 64..127)
    const int k0   = (t & 1) * 32;
    const int atom = side ? edge_src[eidS[e]] : dstS[e];
    const float4* s4 = (const float4*)(atom_states + (size_t)atom * DD + k0);
    const int rowoff = e * SA + side * 64 + k0;
#pragma unroll
    for (int f = 0; f < 8; ++f) {
      float4 v = s4[f];
      ushort4 h, lo;
      h.x = bfbits(v.x); lo.x = bfbits(v.x - bfval(h.x));
      h.y = bfbits(v.y); lo.y = bfbits(v.y - bfval(h.y));
      h.z = bfbits(v.z); lo.z = bfbits(v.z - bfval(h.z));
      h.w = bfbits(v.w); lo.w = bfbits(v.w - bfval(h.w));
      *(ushort4*)&Ahi[rowoff + f * 4] = h;
      *(ushort4*)&Alo[rowoff + f * 4] = lo;
    }
  }
  __syncthreads();

  const int l    = t & 63;
  const int w    = t >> 6;
  const int mrow = w * 16 + (l & 15);   // this lane's A row
  const int kq   = (l >> 4) * 8;        // k-subblock within K=32 step
  const int cc   = l & 15;              // output col within n-tile

  f32x4 acc[4];

  // ---------------- layer 0: K=128 ----------------
#pragma unroll
  for (int j = 0; j < 4; ++j) acc[j] = (f32x4){0.f, 0.f, 0.f, 0.f};
#pragma unroll
  for (int s = 0; s < 4; ++s) {
    bf16x8 ah = ldfrag(&Ahi[mrow * SA + s * 32 + kq]);
    bf16x8 al = ldfrag(&Alo[mrow * SA + s * 32 + kq]);
#pragma unroll
    for (int j = 0; j < 4; ++j) {
      const int fo = ((j * 4 + s) * 64 + l) * 8;
      bf16x8 bh = ldfrag(whi + fo);
      bf16x8 bl = ldfrag(wlo + fo);
      acc[j] = mfma16(al, bh, acc[j]);
      acc[j] = mfma16(ah, bl, acc[j]);
      acc[j] = mfma16(ah, bh, acc[j]);
    }
  }
#pragma unroll
  for (int j = 0; j < 4; ++j) {     // epilogue -> h1 (hi/lo)
    const int   c  = j * 16 + cc;
    const float bb = b0[c];
#pragma unroll
    for (int i = 0; i < 4; ++i) {
      const int r = w * 16 + (l >> 4) * 4 + i;
      float v = relu(acc[j][i] + bb);
      unsigned short hi = bfbits(v);
      Hhi[r * SH + c] = hi;
      Hlo[r * SH + c] = bfbits(v - bfval(hi));
    }
  }
  __syncthreads();

  // ---------------- layer 1: K=64, A=h1, out -> Ahi/Alo ----------------
#pragma unroll
  for (int j = 0; j < 4; ++j) acc[j] = (f32x4){0.f, 0.f, 0.f, 0.f};
#pragma unroll
  for (int s = 0; s < 2; ++s) {
    bf16x8 ah = ldfrag(&Hhi[mrow * SH + s * 32 + kq]);
    bf16x8 al = ldfrag(&Hlo[mrow * SH + s * 32 + kq]);
#pragma unroll
    for (int j = 0; j < 4; ++j) {
      const int fo = 8192 + ((j * 2 + s) * 64 + l) * 8;
      bf16x8 bh = ldfrag(whi + fo);
      bf16x8 bl = ldfrag(wlo + fo);
      acc[j] = mfma16(al, bh, acc[j]);
      acc[j] = mfma16(ah, bl, acc[j]);
      acc[j] = mfma16(ah, bh, acc[j]);
    }
  }
#pragma unroll
  for (int j = 0; j < 4; ++j) {     // epilogue -> h2 in Ahi/Alo
    const int   c  = j * 16 + cc;
    const float bb = b1[c];
#pragma unroll
    for (int i = 0; i < 4; ++i) {
      const int r = w * 16 + (l >> 4) * 4 + i;
      float v = relu(acc[j][i] + bb);
      unsigned short hi = bfbits(v);
      Ahi[r * SA + c] = hi;
      Alo[r * SA + c] = bfbits(v - bfval(hi));
    }
  }
  __syncthreads();

  // ---------------- layer 2: K=64, A=h2, out -> msg (fp32) ----------------
#pragma unroll
  for (int j = 0; j < 4; ++j) acc[j] = (f32x4){0.f, 0.f, 0.f, 0.f};
#pragma unroll
  for (int s = 0; s < 2; ++s) {
    bf16x8 ah = ldfrag(&Ahi[mrow * SA + s * 32 + kq]);
    bf16x8 al = ldfrag(&Alo[mrow * SA + s * 32 + kq]);
#pragma unroll
    for (int j = 0; j < 4; ++j) {
      const int fo = 12288 + ((j * 2 + s) * 64 + l) * 8;
      bf16x8 bh = ldfrag(whi + fo);
      bf16x8 bl = ldfrag(wlo + fo);
      acc[j] = mfma16(al, bh, acc[j]);
      acc[j] = mfma16(ah, bl, acc[j]);
      acc[j] = mfma16(ah, bh, acc[j]);
    }
  }
#pragma unroll
  for (int j = 0; j < 4; ++j) {
    const int   c  = j * 16 + cc;
    const float bb = b2[c];
#pragma unroll
    for (int i = 0; i < 4; ++i) {
      const int r = w * 16 + (l >> 4) * 4 + i;
      msg[r * PADE + c] = relu(acc[j][i] + bb);
    }
  }
  __syncthreads();

  // ---- segmented reduction over dst runs
  {
    const int c = t & 63;
    const int g = t >> 6;
    const int ns = segCount;
    for (int s = g; s < ns; s += 4) {
      const int r0 = segStart[s], r1 = segStart[s + 1];
      float sum = 0.f;
      for (int r = r0; r < r1; ++r) sum += msg[r * PADE + c];
      float* p = new_states + (size_t)dstS[r0] * DD + c;
      if (s == 0 || s == ns - 1) atomicAdd(p, sum);
      else *p = sum;
    }
  }
}

// ===========================================================================
// Fallback fp32 atomic edge kernel (ws too small for sort+weights)
// ===========================================================================
__global__ __launch_bounds__(256, 3)
void edge_kernel_atomic(const float* __restrict__ atom_states,
                        const int* __restrict__ edge_src,
                        const int* __restrict__ edge_dst,
                        const float* __restrict__ w0, const float* __restrict__ b0,
                        const float* __restrict__ w1, const float* __restrict__ b1,
                        const float* __restrict__ w2, const float* __restrict__ b2,
                        float* __restrict__ new_states)
{
  __shared__ float featT[128 * PADE];
  __shared__ float hT[64 * PADE];
  __shared__ float bias[192];

  const int t  = threadIdx.x;
  const int e0 = blockIdx.x * 64;

  if (t < 64) { bias[t] = b0[t]; bias[64 + t] = b1[t]; bias[128 + t] = b2[t]; }
  {
    const int job  = t >> 1;
    const int e    = job & 63;
    const int s    = job >> 6;
    const int k0   = (t & 1) * 32;
    const int atom = (s ? edge_src : edge_dst)[e0 + e];
    const float4* src4 = (const float4*)(atom_states + (size_t)atom * DD + k0);
#pragma unroll
    for (int f = 0; f < 8; ++f) {
      float4 v = src4[f];
      const int kr = s * 64 + k0 + f * 4;
      featT[(kr + 0) * PADE + e] = v.x;
      featT[(kr + 1) * PADE + e] = v.y;
      featT[(kr + 2) * PADE + e] = v.z;
      featT[(kr + 3) * PADE + e] = v.w;
    }
  }
  __syncthreads();

  const int tx = t & 15;
  const int ty = t >> 4;
  float acc[4][4];

  zero4x4(acc);
#pragma unroll 8
  for (int k = 0; k < 128; ++k) {
    float4 a  = *(const float4*)&featT[k * PADE + ty * 4];
    float4 bw = *(const float4*)&w0[k * 64 + tx * 4];
    fma16v(acc, a, bw);
  }
#pragma unroll
  for (int j = 0; j < 4; ++j) {
    const float bb = bias[tx * 4 + j];
    float4 v = make_float4(relu(acc[0][j] + bb), relu(acc[1][j] + bb),
                           relu(acc[2][j] + bb), relu(acc[3][j] + bb));
    *(float4*)&hT[(tx * 4 + j) * PADE + ty * 4] = v;
  }
  __syncthreads();

  zero4x4(acc);
#pragma unroll 8
  for (int k = 0; k < 64; ++k) {
    float4 a  = *(const float4*)&hT[k * PADE + ty * 4];
    float4 bw = *(const float4*)&w1[k * 64 + tx * 4];
    fma16v(acc, a, bw);
  }
#pragma unroll
  for (int j = 0; j < 4; ++j) {
    const float bb = bias[64 + tx * 4 + j];
    float4 v = make_float4(relu(acc[0][j] + bb), relu(acc[1][j] + bb),
                           relu(acc[2][j] + bb), relu(acc[3][j] + bb));
    *(float4*)&featT[(tx * 4 + j) * PADE + ty * 4] = v;
  }
  __syncthreads();

  zero4x4(acc);
#pragma unroll 8
  for (int k = 0; k < 64; ++k) {
    float4 a  = *(const float4*)&featT[k * PADE + ty * 4];
    float4 bw = *(const float4*)&w2[k * 64 + tx * 4];
    fma16v(acc, a, bw);
  }
#pragma unroll
  for (int i = 0; i < 4; ++i) {
    const int dst = edge_dst[e0 + ty * 4 + i];
    float* outp = new_states + (size_t)dst * DD + tx * 4;
#pragma unroll
    for (int j = 0; j < 4; ++j)
      atomicAdd(outp + j, relu(acc[i][j] + bias[128 + tx * 4 + j]));
  }
}

// ===========================================================================
// Atom readout (unchanged): WG = 64 atoms = 2 molecules, fp32.
// ===========================================================================
__global__ __launch_bounds__(256, 4)
void atom_kernel(const float* __restrict__ x,
                 const float* __restrict__ w1, const float* __restrict__ b1,
                 const float* __restrict__ w2, const float* __restrict__ b2,
                 const float* __restrict__ wo, const float* __restrict__ bo,
                 float* __restrict__ out)
{
  __shared__ float xT[64 * PADE];
  __shared__ float hT[64 * PADE];
  __shared__ float oS[64 * 17];
  __shared__ float bias[144];

  const int t  = threadIdx.x;
  const int a0 = blockIdx.x * 64;

  if (t < 64) { bias[t] = b1[t]; bias[64 + t] = b2[t]; }
  if (t < 16) { bias[128 + t] = bo[t]; }

  {
    const int r  = t & 63;
    const int k0 = (t >> 6) * 16;
    const float4* src4 = (const float4*)(x + (size_t)(a0 + r) * DD + k0);
#pragma unroll
    for (int f = 0; f < 4; ++f) {
      float4 v = src4[f];
      const int kr = k0 + f * 4;
      xT[(kr + 0) * PADE + r] = v.x;
      xT[(kr + 1) * PADE + r] = v.y;
      xT[(kr + 2) * PADE + r] = v.z;
      xT[(kr + 3) * PADE + r] = v.w;
    }
  }
  __syncthreads();

  const int tx = t & 15;
  const int ty = t >> 4;
  float acc[4][4];

  zero4x4(acc);
#pragma unroll 8
  for (int k = 0; k < 64; ++k) {
    float4 a  = *(const float4*)&xT[k * PADE + ty * 4];
    float4 bw = *(const float4*)&w1[k * 64 + tx * 4];
    fma16v(acc, a, bw);
  }
#pragma unroll
  for (int j = 0; j < 4; ++j) {
    const float bb = bias[tx * 4 + j];
    float4 v = make_float4(relu(acc[0][j] + bb), relu(acc[1][j] + bb),
                           relu(acc[2][j] + bb), relu(acc[3][j] + bb));
    *(float4*)&hT[(tx * 4 + j) * PADE + ty * 4] = v;
  }
  __syncthreads();

  zero4x4(acc);
#pragma unroll 8
  for (int k = 0; k < 64; ++k) {
    float4 a  = *(const float4*)&hT[k * PADE + ty * 4];
    float4 bw = *(const float4*)&w2[k * 64 + tx * 4];
    fma16v(acc, a, bw);
  }
#pragma unroll
  for (int j = 0; j < 4; ++j) {
    const float bb = bias[64 + tx * 4 + j];
    float4 v = make_float4(relu(acc[0][j] + bb), relu(acc[1][j] + bb),
                           relu(acc[2][j] + bb), relu(acc[3][j] + bb));
    *(float4*)&xT[(tx * 4 + j) * PADE + ty * 4] = v;
  }
  __syncthreads();

  {
    const int r  = t >> 2;
    const int c4 = (t & 3) * 4;
    float o4[4] = {0.f, 0.f, 0.f, 0.f};
#pragma unroll 8
    for (int k = 0; k < 64; ++k) {
      const float a = xT[k * PADE + r];
      float4 bw = *(const float4*)&wo[k * OUTD + c4];
      o4[0] += a * bw.x; o4[1] += a * bw.y; o4[2] += a * bw.z; o4[3] += a * bw.w;
    }
#pragma unroll
    for (int j = 0; j < 4; ++j)
      oS[r * 17 + c4 + j] = relu(o4[j] + bias[128 + c4 + j]);
  }
  __syncthreads();

  if (t < 32) {
    const int m = t >> 4;
    const int c = t & 15;
    float s = 0.f;
#pragma unroll
    for (int a = 0; a < 32; ++a) s += oS[(m * 32 + a) * 17 + c];
    out[(blockIdx.x * 2 + m) * OUTD + c] = s;
  }
}

// ===========================================================================
extern "C" void kernel_launch(void* const* d_in, const int* in_sizes, int n_in,
                              void* d_out, int out_size, void* d_ws, size_t ws_size,
                              hipStream_t stream) {
  const float* atom_states = (const float*)d_in[0];
  const int*   edge_src    = (const int*)d_in[1];
  const int*   edge_dst    = (const int*)d_in[2];
  const float* ms0_w = (const float*)d_in[4];
  const float* ms0_b = (const float*)d_in[5];
  const float* ms1_w = (const float*)d_in[6];
  const float* ms1_b = (const float*)d_in[7];
  const float* ms2_w = (const float*)d_in[8];
  const float* ms2_b = (const float*)d_in[9];
  const float* fc1_w = (const float*)d_in[10];
  const float* fc1_b = (const float*)d_in[11];
  const float* fc2_w = (const float*)d_in[12];
  const float* fc2_b = (const float*)d_in[13];
  const float* out_w = (const float*)d_in[14];
  const float* out_b = (const float*)d_in[15];

  char* ws = (char*)d_ws;
  float* new_states = (float*)ws;
  size_t off = (size_t)N_ATOMS * DD * sizeof(float);              // 32 MiB
  int* eids     = (int*)(ws + off); off += (size_t)N_EDGES * 4;       // +4 MiB
  int* counters = (int*)(ws + off); off += (size_t)N_ATOMS * 4;       // +512 KiB
  int* cursor   = (int*)(ws + off); off += (size_t)N_ATOMS * 4;       // +512 KiB
  int* partial  = (int*)(ws + off); off += 512 * 4;                   // +2 KiB
  unsigned short* whi = (unsigned short*)(ws + off); off += 16384 * 2; // +32 KiB
  unsigned short* wlo = (unsigned short*)(ws + off); off += 16384 * 2; // +32 KiB
  const size_t need = off;

  hipMemsetAsync(new_states, 0, (size_t)N_ATOMS * DD * sizeof(float), stream);

  if (ws_size >= need) {
    hipMemsetAsync(counters, 0, (size_t)N_ATOMS * 4, stream);
    weight_prep<<<8, 256, 0, stream>>>(ms0_w, ms1_w, ms2_w, whi, wlo);
    hist_kernel<<<N_EDGES / 256, 256, 0, stream>>>(edge_dst, counters);
    blocksum_kernel<<<512, 256, 0, stream>>>(counters, partial);
    scanpartial_kernel<<<1, 512, 0, stream>>>(partial);
    scanwrite_kernel<<<512, 256, 0, stream>>>(counters, partial, cursor);
    scatter_kernel<<<N_EDGES / 256, 256, 0, stream>>>(edge_dst, cursor, eids);
    edge_kernel_mfma<<<N_EDGES / 64, 256, 0, stream>>>(
        atom_states, edge_src, edge_dst, eids, whi, wlo,
        ms0_b, ms1_b, ms2_b, new_states);
  } else {
    edge_kernel_atomic<<<N_EDGES / 64, 256, 0, stream>>>(
        atom_states, edge_src, edge_dst,
        ms0_w, ms0_b, ms1_w, ms1_b, ms2_w, ms2_b, new_states);
  }

  atom_kernel<<<N_ATOMS / 64, 256, 0, stream>>>(
      new_states, fc1_w, fc1_b, fc2_w, fc2_b, out_w, out_b, (float*)d_out);
}

// Round 4
// 422.856 us; speedup vs baseline: 2.7298x; 1.3306x over previous
//
#include <hip/hip_runtime.h>

// MessagePassingNet on MI355X — Round 4:
//   * layer-0 hoisted to per-atom precompute (Yd = X·W0d+b0, Ys = X·W0s)
//   * slim edge kernel (h1/h2 only, 37.6 KB LDS -> 4 WGs/CU)
//   * atom readout on MFMA (split-bf16)
//   * counting-sort + segmented reduction as in R2/R3

constexpr int N_ATOMS = 131072;
constexpr int N_EDGES = 1048576;
constexpr int DD      = 64;
constexpr int OUTD    = 16;
constexpr int SH      = 72;   // halfword stride for 64-wide hi/lo LDS tiles
constexpr int SA      = 136;  // halfword stride for 128-wide tier-2 A tiles
constexpr int PADE    = 68;   // fp32 LDS row stride

typedef __bf16 bf16x8 __attribute__((ext_vector_type(8)));
typedef float  f32x4  __attribute__((ext_vector_type(4)));

#define DEV_INLINE __device__ __forceinline__

DEV_INLINE float relu(float x) { return x > 0.f ? x : 0.f; }

DEV_INLINE unsigned short bfbits(float x) {
  __bf16 h = (__bf16)x;
  return __builtin_bit_cast(unsigned short, h);
}
DEV_INLINE float bfval(unsigned short u) {
  unsigned int v = ((unsigned int)u) << 16;
  return __builtin_bit_cast(float, v);
}
DEV_INLINE f32x4 mfma16(bf16x8 a, bf16x8 b, f32x4 c) {
  return __builtin_amdgcn_mfma_f32_16x16x32_bf16(a, b, c, 0, 0, 0);
}
DEV_INLINE bf16x8 ldfrag(const unsigned short* p) { return *(const bf16x8*)p; }

// ===========================================================================
// Counting sort (unchanged)
// ===========================================================================
__global__ void hist_kernel(const int* __restrict__ edge_dst,
                            int* __restrict__ counters) {
  int i = blockIdx.x * blockDim.x + threadIdx.x;
  if (i < N_EDGES) atomicAdd(&counters[edge_dst[i]], 1);
}

__global__ void blocksum_kernel(const int* __restrict__ counters,
                                int* __restrict__ partial) {
  __shared__ int s[256];
  int t = threadIdx.x;
  s[t] = counters[blockIdx.x * 256 + t];
  __syncthreads();
  for (int off = 128; off > 0; off >>= 1) {
    if (t < off) s[t] += s[t + off];
    __syncthreads();
  }
  if (t == 0) partial[blockIdx.x] = s[0];
}

__global__ void scanpartial_kernel(int* __restrict__ partial) {
  __shared__ int s[512];
  int t = threadIdx.x;
  s[t] = partial[t];
  __syncthreads();
  for (int off = 1; off < 512; off <<= 1) {
    int x = (t >= off) ? s[t - off] : 0;
    __syncthreads();
    s[t] += x;
    __syncthreads();
  }
  partial[t] = (t == 0) ? 0 : s[t - 1];
}

__global__ void scanwrite_kernel(const int* __restrict__ counters,
                                 const int* __restrict__ partial,
                                 int* __restrict__ cursor) {
  __shared__ int s[256];
  int t = threadIdx.x, b = blockIdx.x;
  int v = counters[b * 256 + t];
  s[t] = v;
  __syncthreads();
  for (int off = 1; off < 256; off <<= 1) {
    int x = (t >= off) ? s[t - off] : 0;
    __syncthreads();
    s[t] += x;
    __syncthreads();
  }
  cursor[b * 256 + t] = partial[b] + s[t] - v;
}

__global__ void scatter_kernel(const int* __restrict__ edge_dst,
                               int* __restrict__ cursor,
                               int* __restrict__ eids) {
  int i = blockIdx.x * blockDim.x + threadIdx.x;
  if (i < N_EDGES) {
    int pos = atomicAdd(&cursor[edge_dst[i]], 1);
    eids[pos] = i;
  }
}

// ===========================================================================
// Weight prep: 6 sections of 64x64 in B-fragment order, hi/lo split.
//   sec 0: W0 rows  0..63 (dst half)   sec 1: W0 rows 64..127 (src half)
//   sec 2: W1   sec 3: W2   sec 4: FC1   sec 5: FC2
// Fragment (j, s): elem i of lane l -> B[k = s*32+(l>>4)*8+i][n = j*16+(l&15)]
// fo(sec,j,s,l) = sec*4096 + ((j*2+s)*64 + l)*8
// ===========================================================================
__global__ void weight_prep(const float* __restrict__ w0,
                            const float* __restrict__ w1,
                            const float* __restrict__ w2,
                            const float* __restrict__ f1,
                            const float* __restrict__ f2,
                            unsigned short* __restrict__ whi,
                            unsigned short* __restrict__ wlo) {
  int tid = blockIdx.x * blockDim.x + threadIdx.x;   // 0..3071
  int sec = tid >> 9, rel = tid & 511;
  const float* w; int rowoff = 0;
  switch (sec) {
    case 0: w = w0; rowoff = 0;  break;
    case 1: w = w0; rowoff = 64; break;
    case 2: w = w1; break;
    case 3: w = w2; break;
    case 4: w = f1; break;
    default: w = f2; break;
  }
  const int tile = rel >> 6, lane = rel & 63;
  const int j = tile >> 1, s = tile & 1;
  const int n  = j * 16 + (lane & 15);
  const int kb = s * 32 + (lane >> 4) * 8;
  const int out = sec * 4096 + (tile * 64 + lane) * 8;
#pragma unroll
  for (int i = 0; i < 8; ++i) {
    float v = w[(rowoff + kb + i) * 64 + n];
    unsigned short h = bfbits(v);
    whi[out + i] = h;
    wlo[out + i] = bfbits(v - bfval(h));
  }
}

// ===========================================================================
// atom_pre: Yd = X·W0d + b0, Ys = X·W0s per atom (split-bf16 MFMA).
// WG = 64 atoms, in-band row mapping -> zero barriers.
// ===========================================================================
__global__ __launch_bounds__(256, 4)
void atom_pre(const float* __restrict__ X,
              const unsigned short* __restrict__ whi,
              const unsigned short* __restrict__ wlo,
              const float* __restrict__ b0,
              float* __restrict__ Yd, float* __restrict__ Ys)
{
  __shared__ __align__(16) unsigned short Xh[64 * SH];
  __shared__ __align__(16) unsigned short Xl[64 * SH];

  const int t  = threadIdx.x;
  const int a0 = blockIdx.x * 64;

  // stage + split (in-band: row = t>>2 within this wave's 16-row band)
  {
    const int r  = t >> 2;
    const int k0 = (t & 3) * 16;
    const float4* s4 = (const float4*)(X + (size_t)(a0 + r) * DD + k0);
#pragma unroll
    for (int f = 0; f < 4; ++f) {
      float4 v = s4[f];
      ushort4 h, lo;
      h.x = bfbits(v.x); lo.x = bfbits(v.x - bfval(h.x));
      h.y = bfbits(v.y); lo.y = bfbits(v.y - bfval(h.y));
      h.z = bfbits(v.z); lo.z = bfbits(v.z - bfval(h.z));
      h.w = bfbits(v.w); lo.w = bfbits(v.w - bfval(h.w));
      *(ushort4*)&Xh[r * SH + k0 + f * 4] = h;
      *(ushort4*)&Xl[r * SH + k0 + f * 4] = lo;
    }
  }

  const int l    = t & 63;
  const int w    = t >> 6;
  const int mrow = w * 16 + (l & 15);
  const int kq   = (l >> 4) * 8;
  const int cc   = l & 15;

#pragma unroll
  for (int side = 0; side < 2; ++side) {
    f32x4 acc[4];
#pragma unroll
    for (int j = 0; j < 4; ++j) acc[j] = (f32x4){0.f, 0.f, 0.f, 0.f};
#pragma unroll
    for (int s = 0; s < 2; ++s) {
      bf16x8 ah = ldfrag(&Xh[mrow * SH + s * 32 + kq]);
      bf16x8 al = ldfrag(&Xl[mrow * SH + s * 32 + kq]);
#pragma unroll
      for (int j = 0; j < 4; ++j) {
        const int fo = side * 4096 + ((j * 2 + s) * 64 + l) * 8;
        bf16x8 bh = ldfrag(whi + fo);
        bf16x8 bl = ldfrag(wlo + fo);
        acc[j] = mfma16(al, bh, acc[j]);
        acc[j] = mfma16(ah, bl, acc[j]);
        acc[j] = mfma16(ah, bh, acc[j]);
      }
    }
    float* Y = side ? Ys : Yd;
#pragma unroll
    for (int j = 0; j < 4; ++j) {
      const int   c  = j * 16 + cc;
      const float bb = side ? 0.f : b0[c];
#pragma unroll
      for (int i = 0; i < 4; ++i) {
        const int r = w * 16 + (l >> 4) * 4 + i;
        Y[(size_t)(a0 + r) * DD + c] = acc[j][i] + bb;
      }
    }
  }
}

// ===========================================================================
// edge_kernel_v2: WG = 64 dst-sorted edges.
//   h1 = relu(Yd[dst] + Ys[src]) (fused gather) -> L1 -> L2 -> seg reduce.
// In-band wave mapping; 3 barriers. LDS ~37.6 KB -> 4 WGs/CU.
// ===========================================================================
__global__ __launch_bounds__(256, 4)
void edge_kernel_v2(const float* __restrict__ Yd,
                    const float* __restrict__ Ys,
                    const int* __restrict__ edge_src,
                    const int* __restrict__ edge_dst,
                    const int* __restrict__ eids,
                    const unsigned short* __restrict__ whi,
                    const unsigned short* __restrict__ wlo,
                    const float* __restrict__ b1,
                    const float* __restrict__ b2,
                    float* __restrict__ new_states)
{
  __shared__ __align__(16) unsigned short H1[2 * 64 * SH];  // h1 hi|lo; later msg fp32
  __shared__ __align__(16) unsigned short H2[2 * 64 * SH];  // h2 hi|lo
  __shared__ int eidS[64], dstS[64], segStart[65], segCount;

  unsigned short* H1h = H1;
  unsigned short* H1l = H1 + 64 * SH;
  unsigned short* H2h = H2;
  unsigned short* H2l = H2 + 64 * SH;
  float* msg = (float*)H1;   // 64*PADE*4 = 17408 B <= 18432 B

  const int t  = threadIdx.x;
  const int e0 = blockIdx.x * 64;

  if (t < 64) { int e = eids[e0 + t]; eidS[t] = e; dstS[t] = edge_dst[e]; }
  __syncthreads();

  if (t < 64) {   // wave 0: segment detection (consumed after later barriers)
    bool isStart = (t == 0) || (dstS[t] != dstS[t - 1]);
    unsigned long long m = __ballot(isStart);
    if (isStart) {
      unsigned long long below = (t == 0) ? 0ull : (m & ((1ull << t) - 1ull));
      segStart[__popcll(below)] = t;
    }
    if (t == 0) { int ns = __popcll(m); segCount = ns; segStart[ns] = 64; }
  }

  // ---- fused gather: h1 = relu(Yd[dst] + Ys[src]), split hi/lo (in-band)
  {
    const int e  = t >> 2;
    const int k0 = (t & 3) * 16;
    const int dst = dstS[e];
    const int src = edge_src[eidS[e]];
    const float4* pd = (const float4*)(Yd + (size_t)dst * DD + k0);
    const float4* ps = (const float4*)(Ys + (size_t)src * DD + k0);
#pragma unroll
    for (int f = 0; f < 4; ++f) {
      float4 a = pd[f], b = ps[f];
      float4 v = make_float4(relu(a.x + b.x), relu(a.y + b.y),
                             relu(a.z + b.z), relu(a.w + b.w));
      ushort4 h, lo;
      h.x = bfbits(v.x); lo.x = bfbits(v.x - bfval(h.x));
      h.y = bfbits(v.y); lo.y = bfbits(v.y - bfval(h.y));
      h.z = bfbits(v.z); lo.z = bfbits(v.z - bfval(h.z));
      h.w = bfbits(v.w); lo.w = bfbits(v.w - bfval(h.w));
      *(ushort4*)&H1h[e * SH + k0 + f * 4] = h;
      *(ushort4*)&H1l[e * SH + k0 + f * 4] = lo;
    }
  }

  const int l    = t & 63;
  const int w    = t >> 6;
  const int mrow = w * 16 + (l & 15);
  const int kq   = (l >> 4) * 8;
  const int cc   = l & 15;

  f32x4 acc[4];

  // ---- layer 1 (A = h1 in-band, B sec 2) -> h2 hi/lo (in-band)
#pragma unroll
  for (int j = 0; j < 4; ++j) acc[j] = (f32x4){0.f, 0.f, 0.f, 0.f};
#pragma unroll
  for (int s = 0; s < 2; ++s) {
    bf16x8 ah = ldfrag(&H1h[mrow * SH + s * 32 + kq]);
    bf16x8 al = ldfrag(&H1l[mrow * SH + s * 32 + kq]);
#pragma unroll
    for (int j = 0; j < 4; ++j) {
      const int fo = 2 * 4096 + ((j * 2 + s) * 64 + l) * 8;
      bf16x8 bh = ldfrag(whi + fo);
      bf16x8 bl = ldfrag(wlo + fo);
      acc[j] = mfma16(al, bh, acc[j]);
      acc[j] = mfma16(ah, bl, acc[j]);
      acc[j] = mfma16(ah, bh, acc[j]);
    }
  }
#pragma unroll
  for (int j = 0; j < 4; ++j) {
    const int   c  = j * 16 + cc;
    const float bb = b1[c];
#pragma unroll
    for (int i = 0; i < 4; ++i) {
      const int r = w * 16 + (l >> 4) * 4 + i;
      float v = relu(acc[j][i] + bb);
      unsigned short hi = bfbits(v);
      H2h[r * SH + c] = hi;
      H2l[r * SH + c] = bfbits(v - bfval(hi));
    }
  }
  __syncthreads();   // all h1 reads done (msg will alias H1)

  // ---- layer 2 (A = h2 in-band, B sec 3) -> msg fp32 (aliases H1)
#pragma unroll
  for (int j = 0; j < 4; ++j) acc[j] = (f32x4){0.f, 0.f, 0.f, 0.f};
#pragma unroll
  for (int s = 0; s < 2; ++s) {
    bf16x8 ah = ldfrag(&H2h[mrow * SH + s * 32 + kq]);
    bf16x8 al = ldfrag(&H2l[mrow * SH + s * 32 + kq]);
#pragma unroll
    for (int j = 0; j < 4; ++j) {
      const int fo = 3 * 4096 + ((j * 2 + s) * 64 + l) * 8;
      bf16x8 bh = ldfrag(whi + fo);
      bf16x8 bl = ldfrag(wlo + fo);
      acc[j] = mfma16(al, bh, acc[j]);
      acc[j] = mfma16(ah, bl, acc[j]);
      acc[j] = mfma16(ah, bh, acc[j]);
    }
  }
#pragma unroll
  for (int j = 0; j < 4; ++j) {
    const int   c  = j * 16 + cc;
    const float bb = b2[c];
#pragma unroll
    for (int i = 0; i < 4; ++i) {
      const int r = w * 16 + (l >> 4) * 4 + i;
      msg[r * PADE + c] = relu(acc[j][i] + bb);
    }
  }
  __syncthreads();

  // ---- segmented reduction over dst runs
  {
    const int c = t & 63;
    const int g = t >> 6;
    const int ns = segCount;
    for (int s = g; s < ns; s += 4) {
      const int r0 = segStart[s], r1 = segStart[s + 1];
      float sum = 0.f;
      for (int r = r0; r < r1; ++r) sum += msg[r * PADE + c];
      float* p = new_states + (size_t)dstS[r0] * DD + c;
      if (s == 0 || s == ns - 1) atomicAdd(p, sum);
      else *p = sum;
    }
  }
}

// ===========================================================================
// Tier-2 fallback edge kernel (R3 structure, remapped weight offsets):
// full 128-wide layer 0 from atom_states. Used only if ws < Yd/Ys footprint.
// ===========================================================================
__global__ __launch_bounds__(256, 3)
void edge_kernel_t2(const float* __restrict__ atom_states,
                    const int* __restrict__ edge_src,
                    const int* __restrict__ edge_dst,
                    const int* __restrict__ eids,
                    const unsigned short* __restrict__ whi,
                    const unsigned short* __restrict__ wlo,
                    const float* __restrict__ b0,
                    const float* __restrict__ b1,
                    const float* __restrict__ b2,
                    float* __restrict__ new_states)
{
  __shared__ __align__(16) unsigned short Ahi[64 * SA];
  __shared__ __align__(16) unsigned short Alo[64 * SA];
  __shared__ __align__(16) unsigned short Hbuf[2 * 64 * SH];
  __shared__ int eidS[64], dstS[64], segStart[65], segCount;

  unsigned short* Hhi = Hbuf;
  unsigned short* Hlo = Hbuf + 64 * SH;
  float* msg = (float*)Hbuf;

  const int t  = threadIdx.x;
  const int e0 = blockIdx.x * 64;

  if (t < 64) { int e = eids[e0 + t]; eidS[t] = e; dstS[t] = edge_dst[e]; }
  __syncthreads();

  if (t < 64) {
    bool isStart = (t == 0) || (dstS[t] != dstS[t - 1]);
    unsigned long long m = __ballot(isStart);
    if (isStart) {
      unsigned long long below = (t == 0) ? 0ull : (m & ((1ull << t) - 1ull));
      segStart[__popcll(below)] = t;
    }
    if (t == 0) { int ns = __popcll(m); segCount = ns; segStart[ns] = 64; }
  }

  {
    const int job  = t >> 1;
    const int e    = job & 63;
    const int side = job >> 6;
    const int k0   = (t & 1) * 32;
    const int atom = side ? edge_src[eidS[e]] : dstS[e];
    const float4* s4 = (const float4*)(atom_states + (size_t)atom * DD + k0);
    const int rowoff = e * SA + side * 64 + k0;
#pragma unroll
    for (int f = 0; f < 8; ++f) {
      float4 v = s4[f];
      ushort4 h, lo;
      h.x = bfbits(v.x); lo.x = bfbits(v.x - bfval(h.x));
      h.y = bfbits(v.y); lo.y = bfbits(v.y - bfval(h.y));
      h.z = bfbits(v.z); lo.z = bfbits(v.z - bfval(h.z));
      h.w = bfbits(v.w); lo.w = bfbits(v.w - bfval(h.w));
      *(ushort4*)&Ahi[rowoff + f * 4] = h;
      *(ushort4*)&Alo[rowoff + f * 4] = lo;
    }
  }
  __syncthreads();

  const int l    = t & 63;
  const int w    = t >> 6;
  const int mrow = w * 16 + (l & 15);
  const int kq   = (l >> 4) * 8;
  const int cc   = l & 15;

  f32x4 acc[4];

#pragma unroll
  for (int j = 0; j < 4; ++j) acc[j] = (f32x4){0.f, 0.f, 0.f, 0.f};
#pragma unroll
  for (int s = 0; s < 4; ++s) {
    bf16x8 ah = ldfrag(&Ahi[mrow * SA + s * 32 + kq]);
    bf16x8 al = ldfrag(&Alo[mrow * SA + s * 32 + kq]);
#pragma unroll
    for (int j = 0; j < 4; ++j) {
      const int fo = (s < 2 ? 0 : 4096) + ((j * 2 + (s & 1)) * 64 + l) * 8;
      bf16x8 bh = ldfrag(whi + fo);
      bf16x8 bl = ldfrag(wlo + fo);
      acc[j] = mfma16(al, bh, acc[j]);
      acc[j] = mfma16(ah, bl, acc[j]);
      acc[j] = mfma16(ah, bh, acc[j]);
    }
  }
#pragma unroll
  for (int j = 0; j < 4; ++j) {
    const int   c  = j * 16 + cc;
    const float bb = b0[c];
#pragma unroll
    for (int i = 0; i < 4; ++i) {
      const int r = w * 16 + (l >> 4) * 4 + i;
      float v = relu(acc[j][i] + bb);
      unsigned short hi = bfbits(v);
      Hhi[r * SH + c] = hi;
      Hlo[r * SH + c] = bfbits(v - bfval(hi));
    }
  }
  __syncthreads();

#pragma unroll
  for (int j = 0; j < 4; ++j) acc[j] = (f32x4){0.f, 0.f, 0.f, 0.f};
#pragma unroll
  for (int s = 0; s < 2; ++s) {
    bf16x8 ah = ldfrag(&Hhi[mrow * SH + s * 32 + kq]);
    bf16x8 al = ldfrag(&Hlo[mrow * SH + s * 32 + kq]);
#pragma unroll
    for (int j = 0; j < 4; ++j) {
      const int fo = 2 * 4096 + ((j * 2 + s) * 64 + l) * 8;
      bf16x8 bh = ldfrag(whi + fo);
      bf16x8 bl = ldfrag(wlo + fo);
      acc[j] = mfma16(al, bh, acc[j]);
      acc[j] = mfma16(ah, bl, acc[j]);
      acc[j] = mfma16(ah, bh, acc[j]);
    }
  }
#pragma unroll
  for (int j = 0; j < 4; ++j) {
    const int   c  = j * 16 + cc;
    const float bb = b1[c];
#pragma unroll
    for (int i = 0; i < 4; ++i) {
      const int r = w * 16 + (l >> 4) * 4 + i;
      float v = relu(acc[j][i] + bb);
      unsigned short hi = bfbits(v);
      Ahi[r * SA + c] = hi;
      Alo[r * SA + c] = bfbits(v - bfval(hi));
    }
  }
  __syncthreads();

#pragma unroll
  for (int j = 0; j < 4; ++j) acc[j] = (f32x4){0.f, 0.f, 0.f, 0.f};
#pragma unroll
  for (int s = 0; s < 2; ++s) {
    bf16x8 ah = ldfrag(&Ahi[mrow * SA + s * 32 + kq]);
    bf16x8 al = ldfrag(&Alo[mrow * SA + s * 32 + kq]);
#pragma unroll
    for (int j = 0; j < 4; ++j) {
      const int fo = 3 * 4096 + ((j * 2 + s) * 64 + l) * 8;
      bf16x8 bh = ldfrag(whi + fo);
      bf16x8 bl = ldfrag(wlo + fo);
      acc[j] = mfma16(al, bh, acc[j]);
      acc[j] = mfma16(ah, bl, acc[j]);
      acc[j] = mfma16(ah, bh, acc[j]);
    }
  }
#pragma unroll
  for (int j = 0; j < 4; ++j) {
    const int   c  = j * 16 + cc;
    const float bb = b2[c];
#pragma unroll
    for (int i = 0; i < 4; ++i) {
      const int r = w * 16 + (l >> 4) * 4 + i;
      msg[r * PADE + c] = relu(acc[j][i] + bb);
    }
  }
  __syncthreads();

  {
    const int c = t & 63;
    const int g = t >> 6;
    const int ns = segCount;
    for (int s = g; s < ns; s += 4) {
      const int r0 = segStart[s], r1 = segStart[s + 1];
      float sum = 0.f;
      for (int r = r0; r < r1; ++r) sum += msg[r * PADE + c];
      float* p = new_states + (size_t)dstS[r0] * DD + c;
      if (s == 0 || s == ns - 1) atomicAdd(p, sum);
      else *p = sum;
    }
  }
}

// ===========================================================================
// atom_kernel_v2: readout on MFMA (fc1 sec 4, fc2 sec 5) + fp32 out layer +
// in-LDS molecule reduce. Aliased LDS -> ~37.5 KB -> 4 WGs/CU.
// ===========================================================================
__global__ __launch_bounds__(256, 4)
void atom_kernel_v2(const float* __restrict__ ns,
                    const unsigned short* __restrict__ whi,
                    const unsigned short* __restrict__ wlo,
                    const float* __restrict__ f1b,
                    const float* __restrict__ f2b,
                    const float* __restrict__ wo,
                    const float* __restrict__ bo,
                    float* __restrict__ out)
{
  __shared__ __align__(16) unsigned short Xb[2 * 64 * SH];  // x hi|lo; later h2 fp32
  __shared__ __align__(16) unsigned short Hb[2 * 64 * SH];  // h1 hi|lo; later oS
  unsigned short* Xh = Xb;
  unsigned short* Xl = Xb + 64 * SH;
  unsigned short* Hh = Hb;
  unsigned short* Hl = Hb + 64 * SH;
  float* h2f = (float*)Xb;   // 64*PADE*4 = 17408 <= 18432
  float* oS  = (float*)Hb;   // 64*17*4   =  4352 <= 18432

  const int t  = threadIdx.x;
  const int a0 = blockIdx.x * 64;

  // stage + split (in-band)
  {
    const int r  = t >> 2;
    const int k0 = (t & 3) * 16;
    const float4* s4 = (const float4*)(ns + (size_t)(a0 + r) * DD + k0);
#pragma unroll
    for (int f = 0; f < 4; ++f) {
      float4 v = s4[f];
      ushort4 h, lo;
      h.x = bfbits(v.x); lo.x = bfbits(v.x - bfval(h.x));
      h.y = bfbits(v.y); lo.y = bfbits(v.y - bfval(h.y));
      h.z = bfbits(v.z); lo.z = bfbits(v.z - bfval(h.z));
      h.w = bfbits(v.w); lo.w = bfbits(v.w - bfval(h.w));
      *(ushort4*)&Xh[r * SH + k0 + f * 4] = h;
      *(ushort4*)&Xl[r * SH + k0 + f * 4] = lo;
    }
  }

  const int l    = t & 63;
  const int w    = t >> 6;
  const int mrow = w * 16 + (l & 15);
  const int kq   = (l >> 4) * 8;
  const int cc   = l & 15;

  f32x4 acc[4];

  // ---- fc1 (A = X in-band, B sec 4) -> h1 hi/lo (in-band)
#pragma unroll
  for (int j = 0; j < 4; ++j) acc[j] = (f32x4){0.f, 0.f, 0.f, 0.f};
#pragma unroll
  for (int s = 0; s < 2; ++s) {
    bf16x8 ah = ldfrag(&Xh[mrow * SH + s * 32 + kq]);
    bf16x8 al = ldfrag(&Xl[mrow * SH + s * 32 + kq]);
#pragma unroll
    for (int j = 0; j < 4; ++j) {
      const int fo = 4 * 4096 + ((j * 2 + s) * 64 + l) * 8;
      bf16x8 bh = ldfrag(whi + fo);
      bf16x8 bl = ldfrag(wlo + fo);
      acc[j] = mfma16(al, bh, acc[j]);
      acc[j] = mfma16(ah, bl, acc[j]);
      acc[j] = mfma16(ah, bh, acc[j]);
    }
  }
#pragma unroll
  for (int j = 0; j < 4; ++j) {
    const int   c  = j * 16 + cc;
    const float bb = f1b[c];
#pragma unroll
    for (int i = 0; i < 4; ++i) {
      const int r = w * 16 + (l >> 4) * 4 + i;
      float v = relu(acc[j][i] + bb);
      unsigned short hi = bfbits(v);
      Hh[r * SH + c] = hi;
      Hl[r * SH + c] = bfbits(v - bfval(hi));
    }
  }
  __syncthreads();   // all X reads done (h2f will alias Xb)

  // ---- fc2 (A = h1 in-band, B sec 5) -> h2 fp32 (aliases Xb)
#pragma unroll
  for (int j = 0; j < 4; ++j) acc[j] = (f32x4){0.f, 0.f, 0.f, 0.f};
#pragma unroll
  for (int s = 0; s < 2; ++s) {
    bf16x8 ah = ldfrag(&Hh[mrow * SH + s * 32 + kq]);
    bf16x8 al = ldfrag(&Hl[mrow * SH + s * 32 + kq]);
#pragma unroll
    for (int j = 0; j < 4; ++j) {
      const int fo = 5 * 4096 + ((j * 2 + s) * 64 + l) * 8;
      bf16x8 bh = ldfrag(whi + fo);
      bf16x8 bl = ldfrag(wlo + fo);
      acc[j] = mfma16(al, bh, acc[j]);
      acc[j] = mfma16(ah, bl, acc[j]);
      acc[j] = mfma16(ah, bh, acc[j]);
    }
  }
#pragma unroll
  for (int j = 0; j < 4; ++j) {
    const int   c  = j * 16 + cc;
    const float bb = f2b[c];
#pragma unroll
    for (int i = 0; i < 4; ++i) {
      const int r = w * 16 + (l >> 4) * 4 + i;
      h2f[r * PADE + c] = relu(acc[j][i] + bb);
    }
  }
  __syncthreads();   // all h1 reads done (oS will alias Hb)

  // ---- out layer 64x16 (fp32 VALU) -> oS
  {
    const int r  = t >> 2;
    const int c4 = (t & 3) * 4;
    float o4[4] = {0.f, 0.f, 0.f, 0.f};
#pragma unroll 8
    for (int k = 0; k < 64; ++k) {
      const float a = h2f[r * PADE + k];
      float4 bw = *(const float4*)&wo[k * OUTD + c4];
      o4[0] += a * bw.x; o4[1] += a * bw.y; o4[2] += a * bw.z; o4[3] += a * bw.w;
    }
#pragma unroll
    for (int j = 0; j < 4; ++j)
      oS[r * 17 + c4 + j] = relu(o4[j] + bo[c4 + j]);
  }
  __syncthreads();

  // ---- molecule reduction: 2 molecules x 16 cols
  if (t < 32) {
    const int m = t >> 4;
    const int c = t & 15;
    float s = 0.f;
#pragma unroll
    for (int a = 0; a < 32; ++a) s += oS[(m * 32 + a) * 17 + c];
    out[(blockIdx.x * 2 + m) * OUTD + c] = s;
  }
}

// ===========================================================================
extern "C" void kernel_launch(void* const* d_in, const int* in_sizes, int n_in,
                              void* d_out, int out_size, void* d_ws, size_t ws_size,
                              hipStream_t stream) {
  const float* atom_states = (const float*)d_in[0];
  const int*   edge_src    = (const int*)d_in[1];
  const int*   edge_dst    = (const int*)d_in[2];
  const float* ms0_w = (const float*)d_in[4];
  const float* ms0_b = (const float*)d_in[5];
  const float* ms1_w = (const float*)d_in[6];
  const float* ms1_b = (const float*)d_in[7];
  const float* ms2_w = (const float*)d_in[8];
  const float* ms2_b = (const float*)d_in[9];
  const float* fc1_w = (const float*)d_in[10];
  const float* fc1_b = (const float*)d_in[11];
  const float* fc2_w = (const float*)d_in[12];
  const float* fc2_b = (const float*)d_in[13];
  const float* out_w = (const float*)d_in[14];
  const float* out_b = (const float*)d_in[15];

  char* ws = (char*)d_ws;
  float* new_states = (float*)ws;
  size_t off = (size_t)N_ATOMS * DD * sizeof(float);                   // 32 MiB
  int* eids     = (int*)(ws + off); off += (size_t)N_EDGES * 4;        // +4 MiB
  int* counters = (int*)(ws + off); off += (size_t)N_ATOMS * 4;        // +512 KiB
  int* cursor   = (int*)(ws + off); off += (size_t)N_ATOMS * 4;        // +512 KiB
  int* partial  = (int*)(ws + off); off += 4096;                       // +4 KiB
  unsigned short* whi = (unsigned short*)(ws + off); off += 24576 * 2; // +48 KiB
  unsigned short* wlo = (unsigned short*)(ws + off); off += 24576 * 2; // +48 KiB
  const size_t need2 = off;
  float* Yd = (float*)(ws + off); off += (size_t)N_ATOMS * DD * sizeof(float);
  float* Ys = (float*)(ws + off); off += (size_t)N_ATOMS * DD * sizeof(float);
  const size_t need1 = off;   // ~101 MiB

  hipMemsetAsync(new_states, 0, (size_t)N_ATOMS * DD * sizeof(float), stream);
  hipMemsetAsync(counters, 0, (size_t)N_ATOMS * 4, stream);

  weight_prep<<<12, 256, 0, stream>>>(ms0_w, ms1_w, ms2_w, fc1_w, fc2_w, whi, wlo);
  hist_kernel<<<N_EDGES / 256, 256, 0, stream>>>(edge_dst, counters);
  blocksum_kernel<<<512, 256, 0, stream>>>(counters, partial);
  scanpartial_kernel<<<1, 512, 0, stream>>>(partial);
  scanwrite_kernel<<<512, 256, 0, stream>>>(counters, partial, cursor);
  scatter_kernel<<<N_EDGES / 256, 256, 0, stream>>>(edge_dst, cursor, eids);

  if (ws_size >= need1) {
    atom_pre<<<N_ATOMS / 64, 256, 0, stream>>>(atom_states, whi, wlo, ms0_b, Yd, Ys);
    edge_kernel_v2<<<N_EDGES / 64, 256, 0, stream>>>(
        Yd, Ys, edge_src, edge_dst, eids, whi, wlo, ms1_b, ms2_b, new_states);
  } else {
    edge_kernel_t2<<<N_EDGES / 64, 256, 0, stream>>>(
        atom_states, edge_src, edge_dst, eids, whi, wlo,
        ms0_b, ms1_b, ms2_b, new_states);
  }

  atom_kernel_v2<<<N_ATOMS / 64, 256, 0, stream>>>(
      new_states, whi, wlo, fc1_b, fc2_b, out_w, out_b, (float*)d_out);
}